// Round 3
// baseline (32.392 us; speedup 1.0000x reference)
//
#include <hip/hip_runtime.h>

// tensors (1024, 256, 16) fp32, WINDOW=5, STRIDES=1 -> S=252 windows,
// F=16 -> 120 triu pairs. out[b][p][s] fp32.
#define NB 1024
#define NT 256
#define NF 16
#define NW 5
#define NS 252   // NT - NW + 1
#define NPAIR 120
#define GRP 24   // pairs per LDS flush group: 24*252*4B = 24192 B (128B-aligned)
#define NGRP 5   // 120 / 24
#define EPS 1e-5f

typedef float vfloat4 __attribute__((ext_vector_type(4)));

__global__ __launch_bounds__(256) void ts_corr_kernel(const float* __restrict__ in,
                                                      float* __restrict__ out) {
    const int b = blockIdx.x;
    const int tid = threadIdx.x;
    const bool active = tid < NS;
    const int s = active ? tid : NS - 1;  // clamp: inactive lanes compute a dup, skip writes

    __shared__ __align__(16) float vals[GRP * NS];  // 24192 B

    // Load the 5x16 window into registers (vectorized float4 loads).
    const float* row0 = in + ((size_t)b * NT + s) * NF;
    float x[NW][NF];
    #pragma unroll
    for (int w = 0; w < NW; ++w) {
        const float4* r4 = reinterpret_cast<const float4*>(row0 + w * NF);
        #pragma unroll
        for (int q = 0; q < 4; ++q) {
            float4 v = r4[q];
            x[w][q * 4 + 0] = v.x;
            x[w][q * 4 + 1] = v.y;
            x[w][q * 4 + 2] = v.z;
            x[w][q * 4 + 3] = v.w;
        }
    }

    // Per-feature mean and 1/(std+eps), std with ddof=1.
    float mean[NF], rstd[NF];
    #pragma unroll
    for (int i = 0; i < NF; ++i) {
        float sum = 0.f, sq = 0.f;
        #pragma unroll
        for (int w = 0; w < NW; ++w) {
            sum += x[w][i];
            sq  += x[w][i] * x[w][i];
        }
        float m = sum * (1.0f / NW);
        mean[i] = m;
        float var = (sq - (float)NW * m * m) * (1.0f / (NW - 1));
        var = fmaxf(var, 0.0f);
        rstd[i] = 1.0f / (sqrtf(var) + EPS);
    }

    float* outb = out + (size_t)b * (NPAIR * NS);

    // Compute pairs; every GRP pairs, flush through LDS with aligned 16B
    // stores so each 128B line is written whole by one wave instruction.
    int p = 0;
    #pragma unroll
    for (int i = 0; i < NF; ++i) {
        #pragma unroll
        for (int j = i + 1; j < NF; ++j) {
            float sxy = 0.f;
            #pragma unroll
            for (int w = 0; w < NW; ++w) sxy += x[w][i] * x[w][j];
            float cov = sxy * (1.0f / NW) - mean[i] * mean[j];
            float corr = cov * rstd[i] * rstd[j];

            const int g = p / GRP;   // compile-time after unroll
            const int k = p % GRP;
            if (active) vals[k * NS + tid] = corr;

            if (k == GRP - 1) {      // uniform: flush group g
                __syncthreads();
                const int NF4 = GRP * NS / 4;  // 1512 vfloat4 per group
                vfloat4* o4 = reinterpret_cast<vfloat4*>(outb + g * (GRP * NS));
                const vfloat4* v4 = reinterpret_cast<const vfloat4*>(vals);
                #pragma unroll
                for (int it = 0; it < (NF4 + 255) / 256; ++it) {
                    int idx = it * 256 + tid;
                    if (idx < NF4) __builtin_nontemporal_store(v4[idx], &o4[idx]);
                }
                __syncthreads();
            }
            ++p;
        }
    }
}

extern "C" void kernel_launch(void* const* d_in, const int* in_sizes, int n_in,
                              void* d_out, int out_size, void* d_ws, size_t ws_size,
                              hipStream_t stream) {
    const float* in = (const float*)d_in[0];
    float* out = (float*)d_out;
    dim3 grid(NB);
    dim3 block(256);
    ts_corr_kernel<<<grid, block, 0, stream>>>(in, out);
}